// Round 7
// baseline (177.958 us; speedup 1.0000x reference)
//
#include <hip/hip_runtime.h>
#include <hip/hip_bf16.h>

#define N_  2
#define C_  256
#define CK_ 32
#define L_  4096

typedef __attribute__((ext_vector_type(8))) short short8;   // 8 bf16 (4 VGPRs)
typedef __attribute__((ext_vector_type(4))) float f32x4;    // MFMA C/D
typedef __attribute__((ext_vector_type(2))) unsigned int uint2v;
typedef unsigned short ushort;

__device__ __forceinline__ ushort f2bf(float f){
  unsigned u = __float_as_uint(f);
  u += 0x7fffu + ((u >> 16) & 1u);     // RNE
  return (ushort)(u >> 16);
}

__device__ __forceinline__ f32x4 mfma16(short8 a, short8 b, f32x4 c){
  return __builtin_amdgcn_mfma_f32_16x16x32_bf16(a, b, c, 0, 0, 0);
}

// ---------- fused convert: x transpose->bf16 + weights->bf16 ----------
__global__ __launch_bounds__(256) void convert_xw_kernel(
    const float* __restrict__ x1, const float* __restrict__ x2,
    ushort* __restrict__ xT1, ushort* __restrict__ xT2,
    const float* __restrict__ Wk1, const float* __restrict__ Wk2,
    const float* __restrict__ Wv1, const float* __restrict__ Wv2,
    ushort* __restrict__ o1, ushort* __restrict__ o2,
    ushort* __restrict__ o3, ushort* __restrict__ o4){
  int b = blockIdx.x, t = threadIdx.x;
  if (b >= 512){                       // ---- weight tail
    int idx = (b - 512) * 256 + t;
    const int KS = CK_ * C_;           // 8192
    const int VS = C_ * C_;            // 65536
    if (idx < KS)                 o1[idx] = f2bf(Wk1[idx]);
    else if (idx < 2*KS)          o2[idx - KS] = f2bf(Wk2[idx - KS]);
    else if (idx < 2*KS + VS)     o3[idx - 2*KS] = f2bf(Wv1[idx - 2*KS]);
    else if (idx < 2*KS + 2*VS)   o4[idx - 2*KS - VS] = f2bf(Wv2[idx - 2*KS - VS]);
    return;
  }
  __shared__ float tt[32][264];        // [c][l], 33.8 KB, row 1056 B (16-aligned)
  int z = b & 3; int n = z & 1;
  const float* x = (z >> 1) ? x2 : x1;
  ushort* xT = (z >> 1) ? xT2 : xT1;
  int tile = b >> 2;                   // 0..127
  int l0 = (tile & 15) * 256, c0 = (tile >> 4) * 32;
  int w = t >> 6, lam = t & 63;
  const float* xs = x + (size_t)n * C_ * L_;
  ushort* xd = xT + (size_t)n * L_ * C_;
  // phase 1: 32 c-rows, each read as a contiguous 1 KB wave load
#pragma unroll
  for (int k = 0; k < 8; ++k){
    int cr = w * 8 + k;
    float4 f = *(const float4*)(xs + (size_t)(c0 + cr) * L_ + l0 + lam * 4);
    *(float4*)&tt[cr][lam * 4] = f;
  }
  __syncthreads();
  // phase 2: column-gather 8 c's per thread, pack short8, 64 B write runs
  int g = t & 3, lr = t >> 2;          // g: c-group, lr: 0..63
#pragma unroll
  for (int k = 0; k < 4; ++k){
    int l = k * 64 + lr;
    union { __hip_bfloat162 h[4]; short8 v; } pk;
#pragma unroll
    for (int j = 0; j < 4; ++j)
      pk.h[j] = __float22bfloat162_rn(
          make_float2(tt[g*8 + 2*j][l], tt[g*8 + 2*j + 1][l]));
    *(short8*)(xd + (size_t)(l0 + l) * C_ + c0 + g * 8) = pk.v;
  }
}

// V packed layout: per n, 128 pblk (32 p-cols) x 16 cblk (16 c-rows) tiles of
// 512 elts (1 KB). In-tile: elt (c,p) at quad*128 + (c&15)*8 + (p&7), where
// quad = (p&31)>>3. A wave-load of short8 at tile_base + lane*8 (lane =
// quad*16+row) is fully contiguous 1 KB and delivers exactly the PV MFMA
// A-fragment: lane(quad,low) <- V[cblk*16+low][pblk*32 + quad*8 + j].
#define VP_OFF(nn, cc, pp) \
  ((((size_t)(nn)*128 + ((pp)>>5))*16 + ((cc)>>4))*512 + \
   (((pp)&31)>>3)*128 + ((cc)&15)*8 + ((pp)&7))

// ---------- fused projections: k1t/k2t [n][L][CK], v1/v2 packed tiles ----------
__global__ __launch_bounds__(256) void proj_kernel(
    const ushort* __restrict__ xT1, const ushort* __restrict__ xT2,
    const ushort* __restrict__ Wk1b, const ushort* __restrict__ Wk2b,
    const ushort* __restrict__ Wv1b, const ushort* __restrict__ Wv2b,
    const float* __restrict__ bk1, const float* __restrict__ bk2,
    const float* __restrict__ bv1, const float* __restrict__ bv2,
    ushort* __restrict__ k1t, ushort* __restrict__ k2t,
    ushort* __restrict__ v1,  ushort* __restrict__ v2){
  int y = blockIdx.y, n = blockIdx.z;
  int t = threadIdx.x, w = t >> 6, lane = t & 63, quad = lane >> 4, low = lane & 15;
  const ushort* X; const ushort* W; const float* bias; ushort* outp; int jt; bool isK;
  if (y < 8)       { X = xT1; W = Wv1b; bias = bv1; outp = v1;  jt = y;     isK = false; }
  else if (y < 16) { X = xT2; W = Wv2b; bias = bv2; outp = v2;  jt = y - 8; isK = false; }
  else if (y == 16){ X = xT1; W = Wk1b; bias = bk1; outp = k1t; jt = 0;     isK = true; }
  else             { X = xT2; W = Wk2b; bias = bk2; outp = k2t; jt = 0;     isK = true; }
  int j0 = jt * 32;
  int l0 = blockIdx.x * 128 + w * 32;
  const ushort* Xn = X + (size_t)n * L_ * C_;
  f32x4 acc[2][2] = {};
#pragma unroll
  for (int kc = 0; kc < 8; ++kc){
    short8 a[2], b[2];
#pragma unroll
    for (int js = 0; js < 2; ++js)
      a[js] = *(const short8*)(W + (size_t)(j0 + js*16 + low)*C_ + kc*32 + quad*8);
#pragma unroll
    for (int ls = 0; ls < 2; ++ls)
      b[ls] = *(const short8*)(Xn + (size_t)(l0 + ls*16 + low)*C_ + kc*32 + quad*8);
#pragma unroll
    for (int js = 0; js < 2; ++js)
#pragma unroll
      for (int ls = 0; ls < 2; ++ls)
        acc[js][ls] = mfma16(a[js], b[ls], acc[js][ls]);
  }
#pragma unroll
  for (int js = 0; js < 2; ++js){
    f32x4 bb = *(const f32x4*)(bias + j0 + js*16 + quad*4);
#pragma unroll
    for (int ls = 0; ls < 2; ++ls){
      int l = l0 + ls*16 + low;
      if (!isK){
#pragma unroll
        for (int r = 0; r < 4; ++r){
          int c = j0 + js*16 + quad*4 + r;        // output channel
          outp[VP_OFF(n, c, l)] = f2bf(acc[js][ls][r] + bb[r]);
        }
      } else {
        union { ushort u[4]; uint2v v; } pk;
#pragma unroll
        for (int r = 0; r < 4; ++r) pk.u[r] = f2bf(acc[js][ls][r] + bb[r]);
        *(uint2v*)(outp + ((size_t)n*L_ + l)*CK_ + j0 + js*16 + quad*4) = pk.v;
      }
    }
  }
}

// ---------- stats: partial row/col sums of exp(cor) ----------
__global__ __launch_bounds__(256) void stats_kernel(
    const ushort* __restrict__ k1t, const ushort* __restrict__ k2t,
    float* __restrict__ S1part, float* __restrict__ S2part){
  int n = blockIdx.z;
  int m0 = blockIdx.x * 128, l0 = blockIdx.y * 128;
  int t = threadIdx.x, w = t >> 6, lane = t & 63, quad = lane >> 4, low = lane & 15;
  __shared__ float rowsum[128];
  __shared__ float colsum[4][128];
  const ushort* ka = k1t + (size_t)n * L_ * CK_;
  const ushort* kb = k2t + (size_t)n * L_ * CK_;
  short8 a[2], b[8];
#pragma unroll
  for (int lt = 0; lt < 2; ++lt)
    a[lt] = *(const short8*)(ka + (size_t)(l0 + w*32 + lt*16 + low)*CK_ + quad*8);
#pragma unroll
  for (int mt = 0; mt < 8; ++mt)
    b[mt] = *(const short8*)(kb + (size_t)(m0 + mt*16 + low)*CK_ + quad*8);
  float rp[2][4] = {}; float cp[8] = {};
  const f32x4 zero = {0.f, 0.f, 0.f, 0.f};
#pragma unroll
  for (int lt = 0; lt < 2; ++lt)
#pragma unroll
    for (int mt = 0; mt < 8; ++mt){
      f32x4 e = mfma16(a[lt], b[mt], zero);
#pragma unroll
      for (int r = 0; r < 4; ++r){
        float v = __builtin_amdgcn_exp2f(e[r] * 1.44269504088896f);
        rp[lt][r] += v;
        cp[mt] += v;
      }
    }
#pragma unroll
  for (int lt = 0; lt < 2; ++lt)
#pragma unroll
    for (int r = 0; r < 4; ++r){
      float v = rp[lt][r];
      v += __shfl_xor(v, 1); v += __shfl_xor(v, 2);
      v += __shfl_xor(v, 4); v += __shfl_xor(v, 8);
      if (low == 0) rowsum[w*32 + lt*16 + quad*4 + r] = v;
    }
#pragma unroll
  for (int mt = 0; mt < 8; ++mt){
    float v = cp[mt];
    v += __shfl_xor(v, 16); v += __shfl_xor(v, 32);
    if (quad == 0) colsum[w][mt*16 + low] = v;
  }
  __syncthreads();
  if (t < 128)
    S1part[((size_t)n*32 + blockIdx.x)*L_ + l0 + t] = rowsum[t];
  else {
    int m = t - 128;
    S2part[((size_t)n*32 + blockIdx.y)*L_ + m0 + m] =
        colsum[0][m] + colsum[1][m] + colsum[2][m] + colsum[3][m];
  }
}

// ---------- reduce partials -> lsv = log2(1/S) = -log2(S) ----------
__global__ __launch_bounds__(256) void reduce_inv_kernel(
    const float* __restrict__ S1part, const float* __restrict__ S2part,
    float* __restrict__ invS1, float* __restrict__ invS2){
  int idx = blockIdx.x * 256 + threadIdx.x;          // 0..16383
  int which = idx >> 13;
  int r = idx & 8191;                                // n*L + l
  int n = r >> 12, l = r & 4095;
  const float* P = which ? S2part : S1part;
  float s = 0.f;
#pragma unroll
  for (int j = 0; j < 32; ++j) s += P[((size_t)n*32 + j)*L_ + l];
  (which ? invS2 : invS1)[(size_t)n*L_ + l] = -__builtin_amdgcn_logf(s);
}

#define LOG2E_ 1.44269504088896f

// ---------- unified flash r-kernel v9: v8 + c-split x2 for 3 waves/SIMD.
// Diagnosis after v8 (48.7 us): MfmaUtil 36 / VALUBusy 37 / Occupancy 17.5%.
// Issue-cost floor ~920 cy/SIMD-iter vs 3650 measured: ~2700 cy of stall at
// 2 waves/SIMD (register-locked: acc[8][4]=128 AGPR + 112 arch = 240).
// Every structural fix (locality, layout, interleave) left this constant;
// occupancy is the untouched axis. c-tile 128 -> 64: acc[4][4]=64 + ~85 arch
// ~= 150 regs -> 3 waves/SIMD (enforced via __launch_bounds__(256,3)).
// Cost: e-phase/exp duplicated x2 (VALU has headroom), +20% MFMA. V traffic
// unchanged (c-split partitions V). Grid 1024: slice = bid&15 (which,n,cb),
// bid%8 still XCD round-robin; 2 slices/XCD ~= 1.5 MB, L2-fit.
__global__ __launch_bounds__(256, 3) void cross_attn_r_kernel(
    const ushort* __restrict__ k1t, const ushort* __restrict__ k2t,
    const ushort* __restrict__ v1,  const ushort* __restrict__ v2,
    const float* __restrict__ invS1, const float* __restrict__ invS2,
    const float* __restrict__ x1, const float* __restrict__ x2,
    float* __restrict__ out){
  int bid = blockIdx.x;
  int slice = bid & 15;
  int qb = bid >> 4;                   // 0..63
  int n = slice & 1;
  int which = (slice >> 1) & 1;
  int cb = slice >> 2;                 // 0..3 (64-channel block)
  const ushort* kA = which ? k2t : k1t;
  const ushort* kB = which ? k1t : k2t;
  const ushort* V  = which ? v2  : v1;
  const float* iS  = which ? invS2 : invS1;
  const float* X   = which ? x2 : x1;
  float* O = out + (size_t)which * N_ * C_ * L_;
  int q0 = qb * 64, c0 = cb * 64;
  int t = threadIdx.x, w = t >> 6, lane = t & 63, quad = lane >> 4, low = lane & 15;
  __shared__ __align__(16) float red[4][16][68];   // [wave][c_local][q(+pad)]
  const ushort* kAn = kA + (size_t)n * L_ * CK_;
  const ushort* kBn = kB + (size_t)n * L_ * CK_;
  const float*  iSn = iS + (size_t)n * L_;

  // permuted-row A base: A-row m=low -> kA row (m>>2)*8 + (m&3)
  const ushort* kA_base = kAn + (size_t)((low >> 2) * 8 + (low & 3)) * CK_ + quad * 8;
  const float*  sv_base = iSn + quad * 8;
  // packed-V lane base: tiles for this (n, cb) start at cblk = cb*4
  const ushort* Vp_lane = V + ((size_t)n * 128 * 16 + cb * 4) * 512 + (size_t)lane * 8;

  // E-phase B operand (q rows of kB) is loop-invariant: preload once.
  short8 be[4];
#pragma unroll
  for (int qs = 0; qs < 4; ++qs)
    be[qs] = *(const short8*)(kBn + (size_t)(q0 + qs*16 + low) * CK_ + quad * 8);

  f32x4 acc[4][4] = {};
  const f32x4 zero = {0.f, 0.f, 0.f, 0.f};

  // software-pipelined kA-row + scale loads (16 VGPR)
  int pfirst = w * 32;
  short8 a0 = *(const short8*)(kA_base + (size_t)pfirst * CK_);
  short8 a1 = *(const short8*)(kA_base + (size_t)(pfirst + 4) * CK_);
  f32x4 sv0 = *(const f32x4*)(sv_base + pfirst);
  f32x4 sv1 = *(const f32x4*)(sv_base + pfirst + 4);

  for (int kk = 0; kk < L_ / 128; ++kk){
    // V for this iteration: 4 consecutive 1 KB tiles (pblk = kk*4 + w)
    const ushort* vt = Vp_lane + (size_t)(kk*4 + w) * 16 * 512;
    short8 vv[4];
#pragma unroll
    for (int ct = 0; ct < 4; ++ct)
      vv[ct] = *(const short8*)(vt + ct * 512);
    int pn = ((kk + 1) & 31) * 128 + w * 32;   // next-iter kA offset (wraps; harmless)

    // qs-interleaved e->PV: per qs, VALU burst (exp/pack) then MFMA burst (PV)
#pragma unroll
    for (int qs = 0; qs < 4; ++qs){
      f32x4 e0 = mfma16(a0, be[qs], zero);   // rows p+quad*8+r
      f32x4 e1 = mfma16(a1, be[qs], zero);   // rows p+quad*8+4+r
      float p0 = __builtin_amdgcn_exp2f(__fmaf_rn(e0[0], LOG2E_, sv0[0]));
      float p1 = __builtin_amdgcn_exp2f(__fmaf_rn(e0[1], LOG2E_, sv0[1]));
      float p2 = __builtin_amdgcn_exp2f(__fmaf_rn(e0[2], LOG2E_, sv0[2]));
      float p3 = __builtin_amdgcn_exp2f(__fmaf_rn(e0[3], LOG2E_, sv0[3]));
      float p4 = __builtin_amdgcn_exp2f(__fmaf_rn(e1[0], LOG2E_, sv1[0]));
      float p5 = __builtin_amdgcn_exp2f(__fmaf_rn(e1[1], LOG2E_, sv1[1]));
      float p6 = __builtin_amdgcn_exp2f(__fmaf_rn(e1[2], LOG2E_, sv1[2]));
      float p7 = __builtin_amdgcn_exp2f(__fmaf_rn(e1[3], LOG2E_, sv1[3]));
      union { __hip_bfloat162 h[4]; short8 v; } pk;
      pk.h[0] = __float22bfloat162_rn(make_float2(p0, p1));
      pk.h[1] = __float22bfloat162_rn(make_float2(p2, p3));
      pk.h[2] = __float22bfloat162_rn(make_float2(p4, p5));
      pk.h[3] = __float22bfloat162_rn(make_float2(p6, p7));
      short8 pb = pk.v;
      if (qs == 3){
        // a0/a1 dead after this qs's e-MFMAs: prefetch next iter in their
        // latency shadow (sv consumed by the exps above — done now).
        a0 = *(const short8*)(kA_base + (size_t)pn * CK_);
        a1 = *(const short8*)(kA_base + (size_t)(pn + 4) * CK_);
        sv0 = *(const f32x4*)(sv_base + pn);
        sv1 = *(const f32x4*)(sv_base + pn + 4);
      }
      __builtin_amdgcn_s_setprio(1);
#pragma unroll
      for (int ct = 0; ct < 4; ++ct)
        acc[ct][qs] = mfma16(vv[ct], pb, acc[ct][qs]);
      __builtin_amdgcn_s_setprio(0);
    }
  }

  // --- epilogue: cross-wave reduction of the 4 disjoint-p partials + x add
  int cl = t >> 4, qg = (t & 15) * 4;
#pragma unroll
  for (int ct = 0; ct < 4; ++ct){
#pragma unroll
    for (int qs = 0; qs < 4; ++qs)
#pragma unroll
      for (int r = 0; r < 4; ++r)
        red[w][quad*4 + r][qs*16 + low] = acc[ct][qs][r];
    __syncthreads();
    f32x4 s0 = *(const f32x4*)&red[0][cl][qg];
    f32x4 s1 = *(const f32x4*)&red[1][cl][qg];
    f32x4 s2 = *(const f32x4*)&red[2][cl][qg];
    f32x4 s3 = *(const f32x4*)&red[3][cl][qg];
    f32x4 s = (s0 + s1) + (s2 + s3);
    size_t idx = ((size_t)n * C_ + c0 + ct*16 + cl) * L_ + q0 + qg;
    const float4 xv = *(const float4*)(X + idx);
    float4 o = make_float4(xv.x + s[0], xv.y + s[1], xv.z + s[2], xv.w + s[3]);
    *(float4*)(O + idx) = o;
    __syncthreads();
  }
}

extern "C" void kernel_launch(void* const* d_in, const int* in_sizes, int n_in,
                              void* d_out, int out_size, void* d_ws, size_t ws_size,
                              hipStream_t stream) {
  const float* x1  = (const float*)d_in[0];
  const float* x2  = (const float*)d_in[1];
  const float* Wk1 = (const float*)d_in[2];
  const float* bk1 = (const float*)d_in[3];
  const float* Wk2 = (const float*)d_in[4];
  const float* bk2 = (const float*)d_in[5];
  const float* Wv1 = (const float*)d_in[6];
  const float* bv1 = (const float*)d_in[7];
  const float* Wv2 = (const float*)d_in[8];
  const float* bv2 = (const float*)d_in[9];

  char* ws = (char*)d_ws;
  size_t off = 0;
  auto carve = [&](size_t bytes) -> void* {
    void* p = ws + off; off += (bytes + 255) & ~(size_t)255; return p;
  };
  ushort* xT1   = (ushort*)carve((size_t)N_*L_*C_*2);
  ushort* xT2   = (ushort*)carve((size_t)N_*L_*C_*2);
  ushort* Wk1b  = (ushort*)carve((size_t)CK_*C_*2);
  ushort* Wk2b  = (ushort*)carve((size_t)CK_*C_*2);
  ushort* Wv1b  = (ushort*)carve((size_t)C_*C_*2);
  ushort* Wv2b  = (ushort*)carve((size_t)C_*C_*2);
  ushort* k1t   = (ushort*)carve((size_t)N_*L_*CK_*2);
  ushort* k2t   = (ushort*)carve((size_t)N_*L_*CK_*2);
  ushort* v1    = (ushort*)carve((size_t)N_*C_*L_*2);
  ushort* v2    = (ushort*)carve((size_t)N_*C_*L_*2);
  float*  S1p   = (float*)carve((size_t)N_*32*L_*4);
  float*  S2p   = (float*)carve((size_t)N_*32*L_*4);
  float*  invS1 = (float*)carve((size_t)N_*L_*4);
  float*  invS2 = (float*)carve((size_t)N_*L_*4);

  // 512 x-transpose blocks + 576 weight blocks
  convert_xw_kernel<<<dim3(512 + (2*CK_*C_ + 2*C_*C_) / 256), 256, 0, stream>>>(
      x1, x2, xT1, xT2, Wk1, Wk2, Wv1, Wv2, Wk1b, Wk2b, Wv1b, Wv2b);
  proj_kernel<<<dim3(L_/128, 18, N_), 256, 0, stream>>>(
      xT1, xT2, Wk1b, Wk2b, Wv1b, Wv2b, bk1, bk2, bv1, bv2, k1t, k2t, v1, v2);
  stats_kernel<<<dim3(L_/128, L_/128, N_), 256, 0, stream>>>(k1t, k2t, S1p, S2p);
  reduce_inv_kernel<<<dim3(2*N_*L_/256), 256, 0, stream>>>(S1p, S2p, invS1, invS2);
  // grid: 2 which x 2 n x 4 cb x 64 qb = 1024 blocks
  cross_attn_r_kernel<<<dim3(2 * N_ * (C_/64) * (L_/64), 1, 1), 256, 0, stream>>>(
      k1t, k2t, v1, v2, invS1, invS2, x1, x2, (float*)d_out);
}

// Round 8
// 165.637 us; speedup vs baseline: 1.0744x; 1.0744x over previous
//
#include <hip/hip_runtime.h>
#include <hip/hip_bf16.h>

#define N_  2
#define C_  256
#define CK_ 32
#define L_  4096

typedef __attribute__((ext_vector_type(8))) short short8;   // 8 bf16 (4 VGPRs)
typedef __attribute__((ext_vector_type(4))) float f32x4;    // MFMA C/D
typedef __attribute__((ext_vector_type(2))) unsigned int uint2v;
typedef unsigned short ushort;

__device__ __forceinline__ ushort f2bf(float f){
  unsigned u = __float_as_uint(f);
  u += 0x7fffu + ((u >> 16) & 1u);     // RNE
  return (ushort)(u >> 16);
}

__device__ __forceinline__ f32x4 mfma16(short8 a, short8 b, f32x4 c){
  return __builtin_amdgcn_mfma_f32_16x16x32_bf16(a, b, c, 0, 0, 0);
}

// ---------- fused convert: x transpose->bf16 + weights->bf16 ----------
__global__ __launch_bounds__(256) void convert_xw_kernel(
    const float* __restrict__ x1, const float* __restrict__ x2,
    ushort* __restrict__ xT1, ushort* __restrict__ xT2,
    const float* __restrict__ Wk1, const float* __restrict__ Wk2,
    const float* __restrict__ Wv1, const float* __restrict__ Wv2,
    ushort* __restrict__ o1, ushort* __restrict__ o2,
    ushort* __restrict__ o3, ushort* __restrict__ o4){
  int b = blockIdx.x, t = threadIdx.x;
  if (b >= 512){                       // ---- weight tail
    int idx = (b - 512) * 256 + t;
    const int KS = CK_ * C_;           // 8192
    const int VS = C_ * C_;            // 65536
    if (idx < KS)                 o1[idx] = f2bf(Wk1[idx]);
    else if (idx < 2*KS)          o2[idx - KS] = f2bf(Wk2[idx - KS]);
    else if (idx < 2*KS + VS)     o3[idx - 2*KS] = f2bf(Wv1[idx - 2*KS]);
    else if (idx < 2*KS + 2*VS)   o4[idx - 2*KS - VS] = f2bf(Wv2[idx - 2*KS - VS]);
    return;
  }
  __shared__ float tt[32][264];        // [c][l], 33.8 KB, row 1056 B (16-aligned)
  int z = b & 3; int n = z & 1;
  const float* x = (z >> 1) ? x2 : x1;
  ushort* xT = (z >> 1) ? xT2 : xT1;
  int tile = b >> 2;                   // 0..127
  int l0 = (tile & 15) * 256, c0 = (tile >> 4) * 32;
  int w = t >> 6, lam = t & 63;
  const float* xs = x + (size_t)n * C_ * L_;
  ushort* xd = xT + (size_t)n * L_ * C_;
  // phase 1: 32 c-rows, each read as a contiguous 1 KB wave load
#pragma unroll
  for (int k = 0; k < 8; ++k){
    int cr = w * 8 + k;
    float4 f = *(const float4*)(xs + (size_t)(c0 + cr) * L_ + l0 + lam * 4);
    *(float4*)&tt[cr][lam * 4] = f;
  }
  __syncthreads();
  // phase 2: column-gather 8 c's per thread, pack short8, 64 B write runs
  int g = t & 3, lr = t >> 2;          // g: c-group, lr: 0..63
#pragma unroll
  for (int k = 0; k < 4; ++k){
    int l = k * 64 + lr;
    union { __hip_bfloat162 h[4]; short8 v; } pk;
#pragma unroll
    for (int j = 0; j < 4; ++j)
      pk.h[j] = __float22bfloat162_rn(
          make_float2(tt[g*8 + 2*j][l], tt[g*8 + 2*j + 1][l]));
    *(short8*)(xd + (size_t)(l0 + l) * C_ + c0 + g * 8) = pk.v;
  }
}

// V packed layout: per n, 128 pblk (32 p-cols) x 16 cblk (16 c-rows) tiles of
// 512 elts (1 KB). In-tile: elt (c,p) at quad*128 + (c&15)*8 + (p&7), where
// quad = (p&31)>>3. A wave-load of short8 at tile_base + lane*8 (lane =
// quad*16+row) is fully contiguous 1 KB and delivers exactly the PV MFMA
// A-fragment: lane(quad,low) <- V[cblk*16+low][pblk*32 + quad*8 + j].
#define VP_OFF(nn, cc, pp) \
  ((((size_t)(nn)*128 + ((pp)>>5))*16 + ((cc)>>4))*512 + \
   (((pp)&31)>>3)*128 + ((cc)&15)*8 + ((pp)&7))

// ---------- fused projections: k1t/k2t [n][L][CK], v1/v2 packed tiles ----------
__global__ __launch_bounds__(256) void proj_kernel(
    const ushort* __restrict__ xT1, const ushort* __restrict__ xT2,
    const ushort* __restrict__ Wk1b, const ushort* __restrict__ Wk2b,
    const ushort* __restrict__ Wv1b, const ushort* __restrict__ Wv2b,
    const float* __restrict__ bk1, const float* __restrict__ bk2,
    const float* __restrict__ bv1, const float* __restrict__ bv2,
    ushort* __restrict__ k1t, ushort* __restrict__ k2t,
    ushort* __restrict__ v1,  ushort* __restrict__ v2){
  int y = blockIdx.y, n = blockIdx.z;
  int t = threadIdx.x, w = t >> 6, lane = t & 63, quad = lane >> 4, low = lane & 15;
  const ushort* X; const ushort* W; const float* bias; ushort* outp; int jt; bool isK;
  if (y < 8)       { X = xT1; W = Wv1b; bias = bv1; outp = v1;  jt = y;     isK = false; }
  else if (y < 16) { X = xT2; W = Wv2b; bias = bv2; outp = v2;  jt = y - 8; isK = false; }
  else if (y == 16){ X = xT1; W = Wk1b; bias = bk1; outp = k1t; jt = 0;     isK = true; }
  else             { X = xT2; W = Wk2b; bias = bk2; outp = k2t; jt = 0;     isK = true; }
  int j0 = jt * 32;
  int l0 = blockIdx.x * 128 + w * 32;
  const ushort* Xn = X + (size_t)n * L_ * C_;
  f32x4 acc[2][2] = {};
#pragma unroll
  for (int kc = 0; kc < 8; ++kc){
    short8 a[2], b[2];
#pragma unroll
    for (int js = 0; js < 2; ++js)
      a[js] = *(const short8*)(W + (size_t)(j0 + js*16 + low)*C_ + kc*32 + quad*8);
#pragma unroll
    for (int ls = 0; ls < 2; ++ls)
      b[ls] = *(const short8*)(Xn + (size_t)(l0 + ls*16 + low)*C_ + kc*32 + quad*8);
#pragma unroll
    for (int js = 0; js < 2; ++js)
#pragma unroll
      for (int ls = 0; ls < 2; ++ls)
        acc[js][ls] = mfma16(a[js], b[ls], acc[js][ls]);
  }
#pragma unroll
  for (int js = 0; js < 2; ++js){
    f32x4 bb = *(const f32x4*)(bias + j0 + js*16 + quad*4);
#pragma unroll
    for (int ls = 0; ls < 2; ++ls){
      int l = l0 + ls*16 + low;
      if (!isK){
#pragma unroll
        for (int r = 0; r < 4; ++r){
          int c = j0 + js*16 + quad*4 + r;        // output channel
          outp[VP_OFF(n, c, l)] = f2bf(acc[js][ls][r] + bb[r]);
        }
      } else {
        union { ushort u[4]; uint2v v; } pk;
#pragma unroll
        for (int r = 0; r < 4; ++r) pk.u[r] = f2bf(acc[js][ls][r] + bb[r]);
        *(uint2v*)(outp + ((size_t)n*L_ + l)*CK_ + j0 + js*16 + quad*4) = pk.v;
      }
    }
  }
}

// ---------- stats: partial row/col sums of exp(cor) ----------
__global__ __launch_bounds__(256) void stats_kernel(
    const ushort* __restrict__ k1t, const ushort* __restrict__ k2t,
    float* __restrict__ S1part, float* __restrict__ S2part){
  int n = blockIdx.z;
  int m0 = blockIdx.x * 128, l0 = blockIdx.y * 128;
  int t = threadIdx.x, w = t >> 6, lane = t & 63, quad = lane >> 4, low = lane & 15;
  __shared__ float rowsum[128];
  __shared__ float colsum[4][128];
  const ushort* ka = k1t + (size_t)n * L_ * CK_;
  const ushort* kb = k2t + (size_t)n * L_ * CK_;
  short8 a[2], b[8];
#pragma unroll
  for (int lt = 0; lt < 2; ++lt)
    a[lt] = *(const short8*)(ka + (size_t)(l0 + w*32 + lt*16 + low)*CK_ + quad*8);
#pragma unroll
  for (int mt = 0; mt < 8; ++mt)
    b[mt] = *(const short8*)(kb + (size_t)(m0 + mt*16 + low)*CK_ + quad*8);
  float rp[2][4] = {}; float cp[8] = {};
  const f32x4 zero = {0.f, 0.f, 0.f, 0.f};
#pragma unroll
  for (int lt = 0; lt < 2; ++lt)
#pragma unroll
    for (int mt = 0; mt < 8; ++mt){
      f32x4 e = mfma16(a[lt], b[mt], zero);
#pragma unroll
      for (int r = 0; r < 4; ++r){
        float v = __builtin_amdgcn_exp2f(e[r] * 1.44269504088896f);
        rp[lt][r] += v;
        cp[mt] += v;
      }
    }
#pragma unroll
  for (int lt = 0; lt < 2; ++lt)
#pragma unroll
    for (int r = 0; r < 4; ++r){
      float v = rp[lt][r];
      v += __shfl_xor(v, 1); v += __shfl_xor(v, 2);
      v += __shfl_xor(v, 4); v += __shfl_xor(v, 8);
      if (low == 0) rowsum[w*32 + lt*16 + quad*4 + r] = v;
    }
#pragma unroll
  for (int mt = 0; mt < 8; ++mt){
    float v = cp[mt];
    v += __shfl_xor(v, 16); v += __shfl_xor(v, 32);
    if (quad == 0) colsum[w][mt*16 + low] = v;
  }
  __syncthreads();
  if (t < 128)
    S1part[((size_t)n*32 + blockIdx.x)*L_ + l0 + t] = rowsum[t];
  else {
    int m = t - 128;
    S2part[((size_t)n*32 + blockIdx.y)*L_ + m0 + m] =
        colsum[0][m] + colsum[1][m] + colsum[2][m] + colsum[3][m];
  }
}

// ---------- reduce partials -> lsv = log2(1/S) = -log2(S) ----------
__global__ __launch_bounds__(256) void reduce_inv_kernel(
    const float* __restrict__ S1part, const float* __restrict__ S2part,
    float* __restrict__ invS1, float* __restrict__ invS2){
  int idx = blockIdx.x * 256 + threadIdx.x;          // 0..16383
  int which = idx >> 13;
  int r = idx & 8191;                                // n*L + l
  int n = r >> 12, l = r & 4095;
  const float* P = which ? S2part : S1part;
  float s = 0.f;
#pragma unroll
  for (int j = 0; j < 32; ++j) s += P[((size_t)n*32 + j)*L_ + l];
  (which ? invS2 : invS1)[(size_t)n*L_ + l] = -__builtin_amdgcn_logf(s);
}

#define LOG2E_ 1.44269504088896f

// ---------- unified flash r-kernel v10: v8 geometry (c=128, 512 blocks,
// 2 waves/SIMD) + paired-qs schedule with ROTATING V prefetch.
// Round-7 lesson: occupancy axis closed (3 waves/SIMD with doubled e-work
// REGRESSED 48.7->63.2; v9's VALU 52 + MFMA 34 = 86% ~ issue-saturated, so
// extra work = extra time; VALUBusy excludes MFMA). v8's remaining 27% idle
// must be dependency/memory bubbles. The one free lever: v8's V loads issue
// at iter top with first use ~150 cy later (one e-phase) — under L2 latency,
// and vv[ct] stays live through all 4 qs bursts so no earlier slot existed.
// v10: process qs in PAIRS. {e(0),e(1)} -> PV pair over ct -> {e(2),e(3)} +
// kA/sv prefetch -> PV pair 2 where each vv[ct] dies after its 2 MFMAs and
// is reloaded IN PLACE with next iter's tile: V prefetch depth ~600+ cy,
// zero extra vv registers (pb pair live = +4 VGPR, ~244/256 budget).
__global__ __launch_bounds__(256, 2) void cross_attn_r_kernel(
    const ushort* __restrict__ k1t, const ushort* __restrict__ k2t,
    const ushort* __restrict__ v1,  const ushort* __restrict__ v2,
    const float* __restrict__ invS1, const float* __restrict__ invS2,
    const float* __restrict__ x1, const float* __restrict__ x2,
    float* __restrict__ out){
  int bid = blockIdx.x;
  int slice = bid & 7;                 // -> XCD (bid % 8 round-robin)
  int qb = bid >> 3;                   // 0..63
  int n = slice & 1;
  int which = (slice >> 1) & 1;
  int chalf = slice >> 2;
  const ushort* kA = which ? k2t : k1t;
  const ushort* kB = which ? k1t : k2t;
  const ushort* V  = which ? v2  : v1;
  const float* iS  = which ? invS2 : invS1;
  const float* X   = which ? x2 : x1;
  float* O = out + (size_t)which * N_ * C_ * L_;
  int q0 = qb * 64, c0 = chalf * 128;
  int t = threadIdx.x, w = t >> 6, lane = t & 63, quad = lane >> 4, low = lane & 15;
  __shared__ __align__(16) float red[4][16][68];   // [wave][c_local][q(+pad)]
  const ushort* kAn = kA + (size_t)n * L_ * CK_;
  const ushort* kBn = kB + (size_t)n * L_ * CK_;
  const float*  iSn = iS + (size_t)n * L_;

  // permuted-row A base: A-row m=low -> kA row (m>>2)*8 + (m&3)
  const ushort* kA_base = kAn + (size_t)((low >> 2) * 8 + (low & 3)) * CK_ + quad * 8;
  const float*  sv_base = iSn + quad * 8;
  // packed-V lane base: tiles for this (n, chalf) start at cblk = chalf*8
  const ushort* Vp_lane = V + ((size_t)n * 128 * 16 + chalf * 8) * 512 + (size_t)lane * 8;

  // E-phase B operand (q rows of kB) is loop-invariant: preload once.
  short8 be[4];
#pragma unroll
  for (int qs = 0; qs < 4; ++qs)
    be[qs] = *(const short8*)(kBn + (size_t)(q0 + qs*16 + low) * CK_ + quad * 8);

  f32x4 acc[8][4] = {};
  const f32x4 zero = {0.f, 0.f, 0.f, 0.f};

  // software-pipelined kA-row + scale loads (16 VGPR)
  int pfirst = w * 32;
  short8 a0 = *(const short8*)(kA_base + (size_t)pfirst * CK_);
  short8 a1 = *(const short8*)(kA_base + (size_t)(pfirst + 4) * CK_);
  f32x4 sv0 = *(const f32x4*)(sv_base + pfirst);
  f32x4 sv1 = *(const f32x4*)(sv_base + pfirst + 4);

  // V prologue: iter-0 tiles (pblk = w)
  short8 vv[8];
  {
    const ushort* vt0 = Vp_lane + (size_t)w * 16 * 512;
#pragma unroll
    for (int ct = 0; ct < 8; ++ct)
      vv[ct] = *(const short8*)(vt0 + ct * 512);
  }

  // per-qs e-phase: 2 e-MFMAs + 8 exp + pack -> pb
#define EPH(PB, QS) do{                                                        \
    f32x4 e0 = mfma16(a0, be[QS], zero);                                       \
    f32x4 e1 = mfma16(a1, be[QS], zero);                                       \
    float p0 = __builtin_amdgcn_exp2f(__fmaf_rn(e0[0], LOG2E_, sv0[0]));       \
    float p1 = __builtin_amdgcn_exp2f(__fmaf_rn(e0[1], LOG2E_, sv0[1]));       \
    float p2 = __builtin_amdgcn_exp2f(__fmaf_rn(e0[2], LOG2E_, sv0[2]));       \
    float p3 = __builtin_amdgcn_exp2f(__fmaf_rn(e0[3], LOG2E_, sv0[3]));       \
    float p4 = __builtin_amdgcn_exp2f(__fmaf_rn(e1[0], LOG2E_, sv1[0]));       \
    float p5 = __builtin_amdgcn_exp2f(__fmaf_rn(e1[1], LOG2E_, sv1[1]));       \
    float p6 = __builtin_amdgcn_exp2f(__fmaf_rn(e1[2], LOG2E_, sv1[2]));       \
    float p7 = __builtin_amdgcn_exp2f(__fmaf_rn(e1[3], LOG2E_, sv1[3]));       \
    union { __hip_bfloat162 h[4]; short8 v; } pk;                              \
    pk.h[0] = __float22bfloat162_rn(make_float2(p0, p1));                      \
    pk.h[1] = __float22bfloat162_rn(make_float2(p2, p3));                      \
    pk.h[2] = __float22bfloat162_rn(make_float2(p4, p5));                      \
    pk.h[3] = __float22bfloat162_rn(make_float2(p6, p7));                      \
    PB = pk.v;                                                                 \
  }while(0)

  for (int kk = 0; kk < L_ / 256; ++kk){
#pragma unroll
    for (int half = 0; half < 2; ++half){
      int it = 2*kk + half;                         // current iter 0..31
      int itn = (it + 1) & 31;                      // next iter (wraps; harmless)
      const ushort* vt_next = Vp_lane + (size_t)(itn*4 + w) * 16 * 512;
      int pn = itn * 128 + w * 32;
      short8 pb0, pb1;
      // ---- e pair 1
      EPH(pb0, 0);
      EPH(pb1, 1);
      // ---- PV pair 1
      __builtin_amdgcn_s_setprio(1);
#pragma unroll
      for (int ct = 0; ct < 8; ++ct){
        acc[ct][0] = mfma16(vv[ct], pb0, acc[ct][0]);
        acc[ct][1] = mfma16(vv[ct], pb1, acc[ct][1]);
      }
      __builtin_amdgcn_s_setprio(0);
      // ---- e pair 2 (+ kA/sv prefetch after their last use)
      EPH(pb0, 2);
      EPH(pb1, 3);
      a0 = *(const short8*)(kA_base + (size_t)pn * CK_);
      a1 = *(const short8*)(kA_base + (size_t)(pn + 4) * CK_);
      sv0 = *(const f32x4*)(sv_base + pn);
      sv1 = *(const f32x4*)(sv_base + pn + 4);
      // ---- PV pair 2 with rotating next-iter V prefetch
      __builtin_amdgcn_s_setprio(1);
#pragma unroll
      for (int ct = 0; ct < 8; ++ct){
        acc[ct][2] = mfma16(vv[ct], pb0, acc[ct][2]);
        acc[ct][3] = mfma16(vv[ct], pb1, acc[ct][3]);
        vv[ct] = *(const short8*)(vt_next + ct * 512);   // vv[ct] dead: rotate
      }
      __builtin_amdgcn_s_setprio(0);
    }
  }
#undef EPH

  // --- epilogue: cross-wave reduction of the 4 disjoint-p partials + x add
  int cl = t >> 4, qg = (t & 15) * 4;
#pragma unroll
  for (int ct = 0; ct < 8; ++ct){
#pragma unroll
    for (int qs = 0; qs < 4; ++qs)
#pragma unroll
      for (int r = 0; r < 4; ++r)
        red[w][quad*4 + r][qs*16 + low] = acc[ct][qs][r];
    __syncthreads();
    f32x4 s0 = *(const f32x4*)&red[0][cl][qg];
    f32x4 s1 = *(const f32x4*)&red[1][cl][qg];
    f32x4 s2 = *(const f32x4*)&red[2][cl][qg];
    f32x4 s3 = *(const f32x4*)&red[3][cl][qg];
    f32x4 s = (s0 + s1) + (s2 + s3);
    size_t idx = ((size_t)n * C_ + c0 + ct*16 + cl) * L_ + q0 + qg;
    const float4 xv = *(const float4*)(X + idx);
    float4 o = make_float4(xv.x + s[0], xv.y + s[1], xv.z + s[2], xv.w + s[3]);
    *(float4*)(O + idx) = o;
    __syncthreads();
  }
}

extern "C" void kernel_launch(void* const* d_in, const int* in_sizes, int n_in,
                              void* d_out, int out_size, void* d_ws, size_t ws_size,
                              hipStream_t stream) {
  const float* x1  = (const float*)d_in[0];
  const float* x2  = (const float*)d_in[1];
  const float* Wk1 = (const float*)d_in[2];
  const float* bk1 = (const float*)d_in[3];
  const float* Wk2 = (const float*)d_in[4];
  const float* bk2 = (const float*)d_in[5];
  const float* Wv1 = (const float*)d_in[6];
  const float* bv1 = (const float*)d_in[7];
  const float* Wv2 = (const float*)d_in[8];
  const float* bv2 = (const float*)d_in[9];

  char* ws = (char*)d_ws;
  size_t off = 0;
  auto carve = [&](size_t bytes) -> void* {
    void* p = ws + off; off += (bytes + 255) & ~(size_t)255; return p;
  };
  ushort* xT1   = (ushort*)carve((size_t)N_*L_*C_*2);
  ushort* xT2   = (ushort*)carve((size_t)N_*L_*C_*2);
  ushort* Wk1b  = (ushort*)carve((size_t)CK_*C_*2);
  ushort* Wk2b  = (ushort*)carve((size_t)CK_*C_*2);
  ushort* Wv1b  = (ushort*)carve((size_t)C_*C_*2);
  ushort* Wv2b  = (ushort*)carve((size_t)C_*C_*2);
  ushort* k1t   = (ushort*)carve((size_t)N_*L_*CK_*2);
  ushort* k2t   = (ushort*)carve((size_t)N_*L_*CK_*2);
  ushort* v1    = (ushort*)carve((size_t)N_*C_*L_*2);
  ushort* v2    = (ushort*)carve((size_t)N_*C_*L_*2);
  float*  S1p   = (float*)carve((size_t)N_*32*L_*4);
  float*  S2p   = (float*)carve((size_t)N_*32*L_*4);
  float*  invS1 = (float*)carve((size_t)N_*L_*4);
  float*  invS2 = (float*)carve((size_t)N_*L_*4);

  // 512 x-transpose blocks + 576 weight blocks
  convert_xw_kernel<<<dim3(512 + (2*CK_*C_ + 2*C_*C_) / 256), 256, 0, stream>>>(
      x1, x2, xT1, xT2, Wk1, Wk2, Wv1, Wv2, Wk1b, Wk2b, Wv1b, Wv2b);
  proj_kernel<<<dim3(L_/128, 18, N_), 256, 0, stream>>>(
      xT1, xT2, Wk1b, Wk2b, Wv1b, Wv2b, bk1, bk2, bv1, bv2, k1t, k2t, v1, v2);
  stats_kernel<<<dim3(L_/128, L_/128, N_), 256, 0, stream>>>(k1t, k2t, S1p, S2p);
  reduce_inv_kernel<<<dim3(2*N_*L_/256), 256, 0, stream>>>(S1p, S2p, invS1, invS2);
  cross_attn_r_kernel<<<dim3(2 * N_ * (C_/128) * (L_/64), 1, 1), 256, 0, stream>>>(
      k1t, k2t, v1, v2, invS1, invS2, x1, x2, (float*)d_out);
}